// Round 6
// baseline (128.817 us; speedup 1.0000x reference)
//
#include <hip/hip_runtime.h>

#define B_ 32
#define C_ 64          // Cin = Cout
#define H_ 112
#define W_ 112
#define HW (H_ * W_)
#define HTILES 56            // 2-row tiles per image
#define NBLKC (B_ * HTILES)  // 1792, %8==0 for XCD swizzle

#define SLOTS 114            // slot = w+1; slots 0,113 are zeros
#define CHUNK 128            // bytes per (h,slot): 64 cin bf16
#define XROWB (SLOTS * CHUNK)              // 14592 B per (b,h)
#define XT_BYTES ((size_t)B_ * H_ * XROWB) // ~52.3 MB
#define WQ_OFF 131072

typedef short bf16x8 __attribute__((ext_vector_type(8)));
typedef float f32x4 __attribute__((ext_vector_type(4)));
typedef unsigned int u32;

#define GLOAD_LDS(g, l, sz)                                                   \
    __builtin_amdgcn_global_load_lds(                                         \
        (const __attribute__((address_space(1))) u32*)(const void*)(g),       \
        (__attribute__((address_space(3))) u32*)(void*)(l), (sz), 0, 0)

__device__ inline unsigned short f2bf(float f) {
    union { float f; unsigned u; } v;
    v.f = f;
    unsigned u = v.u;
    u += 0x7fffu + ((u >> 16) & 1u);   // RNE
    return (unsigned short)(u >> 16);
}

// w[co][cin][kh][kw] fp32 -> wq[shift][co][cin] bf16 sign
__global__ void quant_w(const float* __restrict__ w,
                        unsigned short* __restrict__ wq) {
    int i = blockIdx.x * 256 + threadIdx.x;
    if (i >= C_ * C_ * 9) return;
    int k   = i % 9;
    int cin = (i / 9) % C_;
    int co  = i / (9 * C_);
    float v = w[i];
    float q = (v > 0.f) ? 1.f : ((v < 0.f) ? -1.f : 0.f);
    wq[(k * C_ + co) * C_ + cin] = f2bf(q);
}

// ---------------------------------------------------------------------------
// Transform: x[b][c][h][w] fp32 -> xt[b][h][slot][cin] bf16, pre-swizzled:
// dword for cin-pair cp at byte (cp*4)^((slot&7)<<4) within the 128-B chunk.
// Measured round 4/5: runs at its HBM floor (~25 us). Unchanged.
// ---------------------------------------------------------------------------
__global__ __launch_bounds__(256) void xform(const float* __restrict__ x,
                                             unsigned short* __restrict__ xt) {
    __shared__ unsigned short pl[C_ * SLOTS];

    const int tid = threadIdx.x;
    const int b   = blockIdx.x / H_;
    const int h   = blockIdx.x % H_;

#pragma unroll
    for (int it = 0; it < 7; ++it) {
        const int u  = tid + 256 * it;        // < 1792 = 64c * 28 quads
        const int c  = u / 28;
        const int w4 = u % 28;
        const f32x4 v =
            *(const f32x4*)(x + ((size_t)(b * C_ + c) * H_ + h) * W_ + w4 * 4);
        const u32 lo = (u32)f2bf(v[0]) | ((u32)f2bf(v[1]) << 16);
        const u32 hi = (u32)f2bf(v[2]) | ((u32)f2bf(v[3]) << 16);
        u32* p = (u32*)&pl[c * SLOTS + w4 * 4];
        p[0] = lo;
        p[1] = hi;
    }
    __syncthreads();

    unsigned short* xtrow = xt + (size_t)(b * H_ + h) * (XROWB / 2);
#pragma unroll
    for (int it = 0; it < 15; ++it) {
        const int u = tid + 256 * it;         // < 3648 = 114 * 32
        if (u < SLOTS * 32) {
            const int slot = u >> 5;
            const int cp   = u & 31;
            u32 val = 0;
            if (1 <= slot && slot <= 112) {
                const int w = slot - 1;
                val = (u32)pl[(2 * cp) * SLOTS + w] |
                      ((u32)pl[(2 * cp + 1) * SLOTS + w] << 16);
            }
            *(u32*)((char*)xtrow + slot * CHUNK +
                    ((cp * 4) ^ ((slot & 7) << 4))) = val;
        }
    }
}

// ---------------------------------------------------------------------------
// Conv implicit GEMM, F=4: wave computes ALL 64 couts for nf = wave+4i
// (14 N-frags = 2 rows x 7 col-groups). LDS stages only rows h0,h0+1
// (29.2 KB); dh-edge B-frags come straight from xt in L2/L3 (VMEM pipe).
// Per B-frag: 4 MFMA (was 2) -> block LDS reads 504 -> 168.
// ---------------------------------------------------------------------------
__global__ __launch_bounds__(256) void conv_mfma(
    const unsigned short* __restrict__ xt, const unsigned short* __restrict__ wq,
    const float* __restrict__ bias, const float* __restrict__ scale,
    float* __restrict__ out) {
    __shared__ char xs[2 * XROWB];   // 29184 B

    const int tid  = threadIdx.x;
    const int lane = tid & 63;
    const int wave = tid >> 6;
    const int lcol = lane & 15;
    const int kg   = lane >> 4;

    const int bid = blockIdx.x;
    const int s   = (bid & 7) * (NBLKC / 8) + (bid >> 3);   // XCD-bijective
    const int b   = s / HTILES;
    const int h0  = (s % HTILES) * 2;

    const char* xtc = (const char*)xt + (size_t)b * H_ * XROWB;

    // ---- stage rows h0, h0+1 (always in-bounds): 2 waves per row ----
    {
        const int row  = wave >> 1;
        const int half = wave & 1;
        const char* src = xtc + (size_t)(h0 + row) * XROWB;
        char* dst = xs + row * XROWB;
        const int boff = half * 7168;
#pragma unroll
        for (int ch = 0; ch < 7; ++ch)
            GLOAD_LDS(src + boff + ch * 1024 + lane * 16,
                      dst + boff + ch * 1024 + lane * 16, 16);
        if (half)   // tail 256 B of the row
            GLOAD_LDS(src + 14336 + lane * 4, dst + 14336 + lane * 4, 4);
    }
    __syncthreads();

    // swizzle-adjusted K-offsets (verified round 4)
    int koff[3][2];
#pragma unroll
    for (int dw = 0; dw < 3; ++dw) {
        const int key = ((lcol + dw) & 7) << 4;
        koff[dw][0] = (kg * 16) ^ key;
        koff[dw][1] = (64 + kg * 16) ^ key;
    }

    f32x4 acc[4][4];   // [i (nf slot)][m (cout frag)]
#pragma unroll
    for (int i = 0; i < 4; ++i)
#pragma unroll
        for (int m = 0; m < 4; ++m) acc[i][m] = (f32x4){0.f, 0.f, 0.f, 0.f};

    const unsigned short* wqa = wq + lcol * C_ + kg * 8;

#pragma unroll
    for (int dh = 0; dh < 3; ++dh) {
#pragma unroll
        for (int dw = 0; dw < 3; ++dw) {
            const unsigned short* wsft = wqa + (dh * 3 + dw) * (C_ * C_);
#pragma unroll
            for (int c0 = 0; c0 < 2; ++c0) {
                bf16x8 af[4];
#pragma unroll
                for (int m = 0; m < 4; ++m)
                    af[m] = *(const bf16x8*)(wsft + m * 16 * C_ + c0 * 32);
#pragma unroll
                for (int i = 0; i < 4; ++i) {
                    const int nf = wave + 4 * i;
                    if (nf < 14) {                       // wave-uniform
                        const int nfr  = (nf >= 7) ? 1 : 0;
                        const int nfc  = nf - 7 * nfr;
                        const int rrel = nfr - 1 + dh;   // -1..2
                        const int slot = nfc * 16 + lcol + dw;
                        const int coff = slot * CHUNK + koff[dw][c0];
                        if (rrel == 0 || rrel == 1) {
                            const bf16x8 bv =
                                *(const bf16x8*)(xs + rrel * XROWB + coff);
#pragma unroll
                            for (int m = 0; m < 4; ++m)
                                acc[i][m] =
                                    __builtin_amdgcn_mfma_f32_16x16x32_bf16(
                                        af[m], bv, acc[i][m], 0, 0, 0);
                        } else {
                            const int r = h0 + rrel;
                            if (0 <= r && r < H_) {      // wave-uniform
                                const bf16x8 bv = *(const bf16x8*)(
                                    xtc + (size_t)r * XROWB + coff);
#pragma unroll
                                for (int m = 0; m < 4; ++m)
                                    acc[i][m] =
                                        __builtin_amdgcn_mfma_f32_16x16x32_bf16(
                                            af[m], bv, acc[i][m], 0, 0, 0);
                            }
                        }
                    }
                }
            }
        }
    }

    // ---- epilogue ----
    const float sc = scale[0];
#pragma unroll
    for (int i = 0; i < 4; ++i) {
        const int nf = wave + 4 * i;
        if (nf < 14) {
            const int nfr = (nf >= 7) ? 1 : 0;
            const int nfc = nf - 7 * nfr;
            const int h   = h0 + nfr;
            const int col = nfc * 16 + lcol;
#pragma unroll
            for (int m = 0; m < 4; ++m) {
                const int cobase = m * 16 + kg * 4;
                const f32x4 bs = *(const f32x4*)(bias + cobase);
#pragma unroll
                for (int rr = 0; rr < 4; ++rr)
                    out[((size_t)(b * C_ + cobase + rr)) * HW + h * W_ + col] =
                        sc * (acc[i][m][rr] + bs[rr]);
            }
        }
    }
}

extern "C" void kernel_launch(void* const* d_in, const int* in_sizes, int n_in,
                              void* d_out, int out_size, void* d_ws,
                              size_t ws_size, hipStream_t stream) {
    const float* x     = (const float*)d_in[0];
    const float* w     = (const float*)d_in[1];
    const float* bias  = (const float*)d_in[2];
    const float* scale = (const float*)d_in[3];
    float* out         = (float*)d_out;

    unsigned short* wq = (unsigned short*)d_ws;   // 73728 B
    unsigned short* xt = (unsigned short*)((char*)d_ws + WQ_OFF);

    quant_w<<<(C_ * C_ * 9 + 255) / 256, 256, 0, stream>>>(w, wq);
    xform<<<B_ * H_, 256, 0, stream>>>(x, xt);
    conv_mfma<<<NBLKC, 256, 0, stream>>>(xt, wq, bias, scale, out);
}

// Round 7
// 112.183 us; speedup vs baseline: 1.1483x; 1.1483x over previous
//
#include <hip/hip_runtime.h>

#define B_ 32
#define C_ 64          // Cin = Cout
#define H_ 112
#define W_ 112
#define HW (H_ * W_)
#define HTILES 56            // 2-row tiles per image
#define NBLKC (B_ * HTILES)  // 1792, %8==0 for XCD swizzle

#define SLOTS 114            // slot = w+1; slots 0,113 are zeros
#define HCH 64               // bytes per (h,half,slot) chunk: 32 cin bf16
#define XHROWB (SLOTS * HCH)               // 7296 B per (b,h,half)
#define XROWB (2 * XHROWB)                 // 14592 B per (b,h)
#define XT_BYTES ((size_t)B_ * H_ * XROWB) // ~52.3 MB
#define WQ_OFF 131072

typedef short bf16x8 __attribute__((ext_vector_type(8)));
typedef float f32x4 __attribute__((ext_vector_type(4)));
typedef unsigned int u32;

#define GLOAD_LDS(g, l, sz)                                                   \
    __builtin_amdgcn_global_load_lds(                                         \
        (const __attribute__((address_space(1))) u32*)(const void*)(g),       \
        (__attribute__((address_space(3))) u32*)(void*)(l), (sz), 0, 0)

__device__ inline unsigned short f2bf(float f) {
    union { float f; unsigned u; } v;
    v.f = f;
    unsigned u = v.u;
    u += 0x7fffu + ((u >> 16) & 1u);   // RNE
    return (unsigned short)(u >> 16);
}

// w[co][cin][kh][kw] fp32 -> wq[shift][co][cin] bf16 sign
__global__ void quant_w(const float* __restrict__ w,
                        unsigned short* __restrict__ wq) {
    int i = blockIdx.x * 256 + threadIdx.x;
    if (i >= C_ * C_ * 9) return;
    int k   = i % 9;
    int cin = (i / 9) % C_;
    int co  = i / (9 * C_);
    float v = w[i];
    float q = (v > 0.f) ? 1.f : ((v < 0.f) ? -1.f : 0.f);
    wq[(k * C_ + co) * C_ + cin] = f2bf(q);
}

// ---------------------------------------------------------------------------
// Transform: x[b][c][h][w] fp32 -> xt[b][h][half][slot][32cin] bf16,
// pre-swizzled: dword for cin-pair cpl at byte (cpl*4)^((slot&3)<<4) within
// the 64-B chunk. Runs at HBM floor (measured rounds 4-6).
// ---------------------------------------------------------------------------
__global__ __launch_bounds__(256) void xform(const float* __restrict__ x,
                                             unsigned short* __restrict__ xt) {
    __shared__ unsigned short pl[C_ * SLOTS];

    const int tid = threadIdx.x;
    const int b   = blockIdx.x / H_;
    const int h   = blockIdx.x % H_;

#pragma unroll
    for (int it = 0; it < 7; ++it) {
        const int u  = tid + 256 * it;        // < 1792 = 64c * 28 quads
        const int c  = u / 28;
        const int w4 = u % 28;
        const f32x4 v =
            *(const f32x4*)(x + ((size_t)(b * C_ + c) * H_ + h) * W_ + w4 * 4);
        const u32 lo = (u32)f2bf(v[0]) | ((u32)f2bf(v[1]) << 16);
        const u32 hi = (u32)f2bf(v[2]) | ((u32)f2bf(v[3]) << 16);
        u32* p = (u32*)&pl[c * SLOTS + w4 * 4];
        p[0] = lo;
        p[1] = hi;
    }
    __syncthreads();

    char* xtrow = (char*)xt + (size_t)(b * H_ + h) * XROWB;
#pragma unroll
    for (int it = 0; it < 15; ++it) {
        const int u = tid + 256 * it;         // < 3648 = 114 slots * 32 cps
        if (u < SLOTS * 32) {
            const int slot = u >> 5;
            const int cp   = u & 31;          // global cin pair
            const int half = cp >> 4;
            const int cpl  = cp & 15;
            u32 val = 0;
            if (1 <= slot && slot <= 112) {
                const int w = slot - 1;
                val = (u32)pl[(2 * cp) * SLOTS + w] |
                      ((u32)pl[(2 * cp + 1) * SLOTS + w] << 16);
            }
            *(u32*)(xtrow + half * XHROWB + slot * HCH +
                    ((cpl * 4) ^ ((slot & 3) << 4))) = val;
        }
    }
}

// ---------------------------------------------------------------------------
// Conv implicit GEMM. Block = (b, 2 output rows), grid 1792.
// Two cin-half phases; per phase LDS holds rows h0-1..h0+2 of one half
// (4 x 7296 = 29184 B -> 4 blocks/CU). F=4: wave computes all 64 couts for
// nf = wave+4i (14 N-frags); every B-frag (ds_read_b128) feeds 4 MFMAs.
// ---------------------------------------------------------------------------
__global__ __launch_bounds__(256, 4) void conv_mfma(
    const unsigned short* __restrict__ xt, const unsigned short* __restrict__ wq,
    const float* __restrict__ bias, const float* __restrict__ scale,
    float* __restrict__ out) {
    __shared__ char xs[4 * XHROWB];   // 29184 B

    const int tid  = threadIdx.x;
    const int lane = tid & 63;
    const int wave = tid >> 6;
    const int lcol = lane & 15;
    const int kg   = lane >> 4;

    const int bid = blockIdx.x;
    const int s   = (bid & 7) * (NBLKC / 8) + (bid >> 3);   // XCD-bijective
    const int b   = s / HTILES;
    const int h0  = (s % HTILES) * 2;

    const char* xtc = (const char*)xt + (size_t)b * H_ * XROWB;

    // swizzle-adjusted K-offset: slot&3 == (lcol+dw)&3
    int koff[3];
#pragma unroll
    for (int dw = 0; dw < 3; ++dw)
        koff[dw] = (kg * 16) ^ (((lcol + dw) & 3) << 4);

    f32x4 acc[4][4];   // [i (nf slot)][m (cout frag)]
#pragma unroll
    for (int i = 0; i < 4; ++i)
#pragma unroll
        for (int m = 0; m < 4; ++m) acc[i][m] = (f32x4){0.f, 0.f, 0.f, 0.f};

    const int xrow = h0 - 1 + wave;            // row this wave stages
    const bool inb = (0 <= xrow) && (xrow < H_);
    char* dst = xs + wave * XHROWB;

#pragma unroll
    for (int ph = 0; ph < 2; ++ph) {
        if (ph) __syncthreads();   // phase-0 reads done before overwrite

        // ---- stage: wave r copies row h0-1+r, half ph (7296 B) ----
        if (inb) {
            const char* src = xtc + (size_t)xrow * XROWB + ph * XHROWB;
#pragma unroll
            for (int ch = 0; ch < 7; ++ch)
                GLOAD_LDS(src + ch * 1024 + lane * 16,
                          dst + ch * 1024 + lane * 16, 16);
            if (lane < 32)   // tail 128 B
                GLOAD_LDS(src + 7168 + lane * 4, dst + 7168 + lane * 4, 4);
        } else if (ph == 0) {      // zero once; stays zero both phases
            char* d = dst + lane * 16;
            const f32x4 z = {0.f, 0.f, 0.f, 0.f};
#pragma unroll
            for (int ch = 0; ch < 7; ++ch) *(f32x4*)(d + ch * 1024) = z;
            if (lane < 32) *(u32*)(dst + 7168 + lane * 4) = 0u;
        }
        __syncthreads();

        const unsigned short* wqa = wq + lcol * C_ + ph * 32 + kg * 8;

#pragma unroll
        for (int dh = 0; dh < 3; ++dh) {
#pragma unroll
            for (int dw = 0; dw < 3; ++dw) {
                const unsigned short* wsft = wqa + (dh * 3 + dw) * (C_ * C_);
                bf16x8 af[4];
#pragma unroll
                for (int m = 0; m < 4; ++m)
                    af[m] = *(const bf16x8*)(wsft + m * 16 * C_);
#pragma unroll
                for (int i = 0; i < 4; ++i) {
                    const int nf = wave + 4 * i;
                    if (nf < 14) {                     // wave-uniform guard
                        const int nfr  = (nf >= 7) ? 1 : 0;
                        const int nfc  = nf - 7 * nfr;
                        const int slot = nfc * 16 + lcol + dw;
                        const bf16x8 bv = *(const bf16x8*)(
                            xs + (nfr + dh) * XHROWB + slot * HCH + koff[dw]);
#pragma unroll
                        for (int m = 0; m < 4; ++m)
                            acc[i][m] =
                                __builtin_amdgcn_mfma_f32_16x16x32_bf16(
                                    af[m], bv, acc[i][m], 0, 0, 0);
                    }
                }
            }
        }
    }

    // ---- epilogue ----
    const float sc = scale[0];
#pragma unroll
    for (int i = 0; i < 4; ++i) {
        const int nf = wave + 4 * i;
        if (nf < 14) {
            const int nfr = (nf >= 7) ? 1 : 0;
            const int nfc = nf - 7 * nfr;
            const int h   = h0 + nfr;
            const int col = nfc * 16 + lcol;
#pragma unroll
            for (int m = 0; m < 4; ++m) {
                const int cobase = m * 16 + kg * 4;
                const f32x4 bs = *(const f32x4*)(bias + cobase);
#pragma unroll
                for (int rr = 0; rr < 4; ++rr)
                    out[((size_t)(b * C_ + cobase + rr)) * HW + h * W_ + col] =
                        sc * (acc[i][m][rr] + bs[rr]);
            }
        }
    }
}

extern "C" void kernel_launch(void* const* d_in, const int* in_sizes, int n_in,
                              void* d_out, int out_size, void* d_ws,
                              size_t ws_size, hipStream_t stream) {
    const float* x     = (const float*)d_in[0];
    const float* w     = (const float*)d_in[1];
    const float* bias  = (const float*)d_in[2];
    const float* scale = (const float*)d_in[3];
    float* out         = (float*)d_out;

    unsigned short* wq = (unsigned short*)d_ws;   // 73728 B
    unsigned short* xt = (unsigned short*)((char*)d_ws + WQ_OFF);

    quant_w<<<(C_ * C_ * 9 + 255) / 256, 256, 0, stream>>>(w, wq);
    xform<<<B_ * H_, 256, 0, stream>>>(x, xt);
    conv_mfma<<<NBLKC, 256, 0, stream>>>(xt, wq, bias, scale, out);
}